// Round 1
// baseline (1605.525 us; speedup 1.0000x reference)
//
#include <hip/hip_runtime.h>

#define F_IN 512
#define HID  16
#define NCLS 40

// deg[i] = 1.0 (self-loop contribution)
__global__ void k_init_deg(float* __restrict__ deg, int n) {
    int i = blockIdx.x * blockDim.x + threadIdx.x;
    if (i < n) deg[i] = 1.0f;
}

// deg[col[e]] += 1
__global__ void k_count_deg(const int* __restrict__ col, float* __restrict__ deg, int ne) {
    int e = blockIdx.x * blockDim.x + threadIdx.x;
    if (e < ne) atomicAdd(&deg[col[e]], 1.0f);
}

// deg -> rsqrt(deg), in place
__global__ void k_dinv(float* __restrict__ deg, int n) {
    int i = blockIdx.x * blockDim.x + threadIdx.x;
    if (i < n) deg[i] = rsqrtf(deg[i]);
}

// y = x @ W1  (per-thread node, W1 reads are lane-uniform -> scalar cache)
// agg1 = y * dinv[n]^2   (self-loop term initializes the accumulator)
__global__ void k_gemm1(const float* __restrict__ x, const float* __restrict__ W1,
                        const float* __restrict__ dinv, float* __restrict__ y,
                        float* __restrict__ agg1, int n) {
    int node = blockIdx.x * blockDim.x + threadIdx.x;
    if (node >= n) return;
    const float* xr = x + (size_t)node * F_IN;
    float acc[HID];
#pragma unroll
    for (int j = 0; j < HID; ++j) acc[j] = 0.f;
    for (int k = 0; k < F_IN; k += 4) {
        float4 xv = *reinterpret_cast<const float4*>(xr + k);
        const float* w = W1 + (size_t)k * HID;
#pragma unroll
        for (int j = 0; j < HID; ++j) acc[j] = fmaf(xv.x, w[j], acc[j]);
#pragma unroll
        for (int j = 0; j < HID; ++j) acc[j] = fmaf(xv.y, w[HID + j], acc[j]);
#pragma unroll
        for (int j = 0; j < HID; ++j) acc[j] = fmaf(xv.z, w[2 * HID + j], acc[j]);
#pragma unroll
        for (int j = 0; j < HID; ++j) acc[j] = fmaf(xv.w, w[3 * HID + j], acc[j]);
    }
    float di = dinv[node];
    float sl = di * di;
    float4* yo = reinterpret_cast<float4*>(y + (size_t)node * HID);
    float4* ao = reinterpret_cast<float4*>(agg1 + (size_t)node * HID);
#pragma unroll
    for (int q = 0; q < 4; ++q) {
        float4 v = make_float4(acc[4 * q], acc[4 * q + 1], acc[4 * q + 2], acc[4 * q + 3]);
        yo[q] = v;
        ao[q] = make_float4(v.x * sl, v.y * sl, v.z * sl, v.w * sl);
    }
}

// 4 lanes per edge; each lane: float4 gather from src[row], 4x atomicAdd into dst[col]
__global__ void k_scatter(const int* __restrict__ row, const int* __restrict__ col,
                          const float* __restrict__ dinv, const float* __restrict__ src,
                          float* __restrict__ dst, int ne) {
    int t = blockIdx.x * blockDim.x + threadIdx.x;
    int e = t >> 2;
    if (e >= ne) return;
    int q = (t & 3) << 2;
    int r = row[e], c = col[e];
    float w = dinv[r] * dinv[c];
    float4 v = *reinterpret_cast<const float4*>(src + (size_t)r * HID + q);
    float* d = dst + (size_t)c * HID + q;
    atomicAdd(d + 0, v.x * w);
    atomicAdd(d + 1, v.y * w);
    atomicAdd(d + 2, v.z * w);
    atomicAdd(d + 3, v.w * w);
}

// h1 = relu(agg1 + b1) in place; agg2 = h1 * dinv^2 (self-loop init for layer 2)
__global__ void k_relu_prep(float* __restrict__ agg1, const float* __restrict__ b1,
                            const float* __restrict__ dinv, float* __restrict__ agg2,
                            int total) {
    int i = blockIdx.x * blockDim.x + threadIdx.x;
    if (i >= total) return;
    int node = i >> 4;
    int j = i & 15;
    float v = agg1[i] + b1[j];
    v = fmaxf(v, 0.f);
    agg1[i] = v;
    float di = dinv[node];
    agg2[i] = v * di * di;
}

// out = log_softmax(agg2 @ W2 + b2)
__global__ void k_final(const float* __restrict__ agg2, const float* __restrict__ W2,
                        const float* __restrict__ b2, float* __restrict__ out, int n) {
    int node = blockIdx.x * blockDim.x + threadIdx.x;
    if (node >= n) return;
    const float4* ar = reinterpret_cast<const float4*>(agg2 + (size_t)node * HID);
    float a[HID];
#pragma unroll
    for (int q = 0; q < 4; ++q) {
        float4 t = ar[q];
        a[4 * q] = t.x; a[4 * q + 1] = t.y; a[4 * q + 2] = t.z; a[4 * q + 3] = t.w;
    }
    float z[NCLS];
#pragma unroll
    for (int j = 0; j < NCLS; ++j) z[j] = b2[j];
#pragma unroll
    for (int i = 0; i < HID; ++i) {
        const float* w = W2 + (size_t)i * NCLS;
        float ai = a[i];
#pragma unroll
        for (int j = 0; j < NCLS; ++j) z[j] = fmaf(ai, w[j], z[j]);
    }
    float m = z[0];
#pragma unroll
    for (int j = 1; j < NCLS; ++j) m = fmaxf(m, z[j]);
    float s = 0.f;
#pragma unroll
    for (int j = 0; j < NCLS; ++j) s += __expf(z[j] - m);
    float ls = m + __logf(s);
    float* o = out + (size_t)node * NCLS;
#pragma unroll
    for (int q = 0; q < NCLS / 4; ++q) {
        float4 v = make_float4(z[4 * q] - ls, z[4 * q + 1] - ls,
                               z[4 * q + 2] - ls, z[4 * q + 3] - ls);
        *reinterpret_cast<float4*>(o + 4 * q) = v;
    }
}

extern "C" void kernel_launch(void* const* d_in, const int* in_sizes, int n_in,
                              void* d_out, int out_size, void* d_ws, size_t ws_size,
                              hipStream_t stream) {
    const float* x  = (const float*)d_in[0];
    const int*   ei = (const int*)d_in[1];
    const float* b1 = (const float*)d_in[3];
    const float* W1 = (const float*)d_in[2];
    const float* W2 = (const float*)d_in[4];
    const float* b2 = (const float*)d_in[5];
    float* out = (float*)d_out;

    const int N = in_sizes[0] / F_IN;   // 100000
    const int E = in_sizes[1] / 2;      // 3200000
    const int* row = ei;        // source nodes
    const int* col = ei + E;    // target nodes

    float* ws   = (float*)d_ws;
    float* dinv = ws;                        // N floats (deg, then rsqrt in place)
    float* y    = dinv + N;                  // N*16
    float* agg1 = y + (size_t)N * HID;       // N*16 (becomes h1 after relu)
    float* agg2 = agg1 + (size_t)N * HID;    // N*16

    const int B = 256;
    k_init_deg <<<(N + B - 1) / B, B, 0, stream>>>(dinv, N);
    k_count_deg<<<(E + B - 1) / B, B, 0, stream>>>(col, dinv, E);
    k_dinv     <<<(N + B - 1) / B, B, 0, stream>>>(dinv, N);
    k_gemm1    <<<(N + B - 1) / B, B, 0, stream>>>(x, W1, dinv, y, agg1, N);
    k_scatter  <<<((E * 4) + B - 1) / B, B, 0, stream>>>(row, col, dinv, y, agg1, E);
    k_relu_prep<<<((N * HID) + B - 1) / B, B, 0, stream>>>(agg1, b1, dinv, agg2, N * HID);
    k_scatter  <<<((E * 4) + B - 1) / B, B, 0, stream>>>(row, col, dinv, agg1, agg2, E);
    k_final    <<<(N + B - 1) / B, B, 0, stream>>>(agg2, W2, b2, out, N);
}

// Round 2
// 900.461 us; speedup vs baseline: 1.7830x; 1.7830x over previous
//
#include <hip/hip_runtime.h>

#define F_IN 512
#define HID  16
#define NCLS 40

__global__ void k_zero_i(int* __restrict__ p, int n) {
    int i = blockIdx.x * blockDim.x + threadIdx.x;
    if (i < n) p[i] = 0;
}

// cnt[col[e]] += 1  (int atomics, 1 per edge)
__global__ void k_hist(const int* __restrict__ col, int* __restrict__ cnt, int ne) {
    int e = blockIdx.x * blockDim.x + threadIdx.x;
    if (e < ne) atomicAdd(&cnt[col[e]], 1);
}

// single-block exclusive scan of cnt -> ptr; cur = ptr copy; dinv = rsqrt(cnt+1)
__global__ void k_scan(const int* __restrict__ cnt, int* __restrict__ ptr,
                       int* __restrict__ cur, float* __restrict__ dinv, int n) {
    __shared__ int sh[1024];
    int t = threadIdx.x;
    const int CH = (n + 1023) >> 10;
    int lo = t * CH, hi = lo + CH;
    if (lo > n) lo = n;
    if (hi > n) hi = n;
    int s = 0;
    for (int i = lo; i < hi; ++i) s += cnt[i];
    sh[t] = s;
    __syncthreads();
    // Hillis-Steele inclusive scan
    for (int off = 1; off < 1024; off <<= 1) {
        int v = (t >= off) ? sh[t - off] : 0;
        __syncthreads();
        sh[t] += v;
        __syncthreads();
    }
    int run = (t == 0) ? 0 : sh[t - 1];
    for (int i = lo; i < hi; ++i) {
        int c = cnt[i];
        ptr[i] = run;
        cur[i] = run;
        dinv[i] = rsqrtf((float)(c + 1));
        run += c;
    }
    if (t == 1023) ptr[n] = run;  // == E
}

// rows_sorted[cur[col[e]]++] = row[e]
__global__ void k_fill(const int* __restrict__ row, const int* __restrict__ col,
                       int* __restrict__ cur, int* __restrict__ rows_sorted, int ne) {
    int e = blockIdx.x * blockDim.x + threadIdx.x;
    if (e >= ne) return;
    int c = col[e];
    int p = atomicAdd(&cur[c], 1);
    rows_sorted[p] = row[e];
}

// yp = dinv[node] * (x @ W1)   (prescaled by source dinv)
__global__ void k_gemm1(const float* __restrict__ x, const float* __restrict__ W1,
                        const float* __restrict__ dinv, float* __restrict__ yp, int n) {
    int node = blockIdx.x * blockDim.x + threadIdx.x;
    if (node >= n) return;
    const float* xr = x + (size_t)node * F_IN;
    float acc[HID];
#pragma unroll
    for (int j = 0; j < HID; ++j) acc[j] = 0.f;
    for (int k = 0; k < F_IN; k += 4) {
        float4 xv = *reinterpret_cast<const float4*>(xr + k);
        const float* w = W1 + (size_t)k * HID;
#pragma unroll
        for (int j = 0; j < HID; ++j) acc[j] = fmaf(xv.x, w[j], acc[j]);
#pragma unroll
        for (int j = 0; j < HID; ++j) acc[j] = fmaf(xv.y, w[HID + j], acc[j]);
#pragma unroll
        for (int j = 0; j < HID; ++j) acc[j] = fmaf(xv.z, w[2 * HID + j], acc[j]);
#pragma unroll
        for (int j = 0; j < HID; ++j) acc[j] = fmaf(xv.w, w[3 * HID + j], acc[j]);
    }
    float di = dinv[node];
    float4* o = reinterpret_cast<float4*>(yp + (size_t)node * HID);
#pragma unroll
    for (int q = 0; q < 4; ++q)
        o[q] = make_float4(acc[4 * q] * di, acc[4 * q + 1] * di,
                           acc[4 * q + 2] * di, acc[4 * q + 3] * di);
}

// Gather-reduce over CSR segment. 4 lanes per node, each lane owns a float4.
// acc = src[node] + sum over in-edges src[r];  out:
//   RELU: dst = dinv * relu(dinv*acc + b1)    (prescaled hidden for layer 2)
//   else: dst = dinv * acc                    (final pre-W2 features)
template <bool RELU>
__global__ void k_agg(const int* __restrict__ ptr, const int* __restrict__ rows_sorted,
                      const float* __restrict__ src, const float* __restrict__ dinv,
                      const float* __restrict__ b1, float* __restrict__ dst, int n) {
    int t = blockIdx.x * blockDim.x + threadIdx.x;
    int g = t >> 2;            // node
    if (g >= n) return;
    int q = (t & 3) << 2;      // float4 slot
    float4 acc = *reinterpret_cast<const float4*>(src + (size_t)g * HID + q);
    int s = ptr[g], e2 = ptr[g + 1];
    int k = s;
    for (; k + 1 < e2; k += 2) {
        int r0 = rows_sorted[k], r1 = rows_sorted[k + 1];
        float4 v0 = *reinterpret_cast<const float4*>(src + (size_t)r0 * HID + q);
        float4 v1 = *reinterpret_cast<const float4*>(src + (size_t)r1 * HID + q);
        acc.x += v0.x + v1.x; acc.y += v0.y + v1.y;
        acc.z += v0.z + v1.z; acc.w += v0.w + v1.w;
    }
    if (k < e2) {
        int r0 = rows_sorted[k];
        float4 v0 = *reinterpret_cast<const float4*>(src + (size_t)r0 * HID + q);
        acc.x += v0.x; acc.y += v0.y; acc.z += v0.z; acc.w += v0.w;
    }
    float d = dinv[g];
    float4 o;
    if (RELU) {
        float4 bb = *reinterpret_cast<const float4*>(b1 + q);
        o.x = d * fmaxf(fmaf(d, acc.x, bb.x), 0.f);
        o.y = d * fmaxf(fmaf(d, acc.y, bb.y), 0.f);
        o.z = d * fmaxf(fmaf(d, acc.z, bb.z), 0.f);
        o.w = d * fmaxf(fmaf(d, acc.w, bb.w), 0.f);
    } else {
        o.x = d * acc.x; o.y = d * acc.y; o.z = d * acc.z; o.w = d * acc.w;
    }
    *reinterpret_cast<float4*>(dst + (size_t)g * HID + q) = o;
}

// out = log_softmax(agg2 @ W2 + b2)
__global__ void k_final(const float* __restrict__ agg2, const float* __restrict__ W2,
                        const float* __restrict__ b2, float* __restrict__ out, int n) {
    int node = blockIdx.x * blockDim.x + threadIdx.x;
    if (node >= n) return;
    const float4* ar = reinterpret_cast<const float4*>(agg2 + (size_t)node * HID);
    float a[HID];
#pragma unroll
    for (int q = 0; q < 4; ++q) {
        float4 t = ar[q];
        a[4 * q] = t.x; a[4 * q + 1] = t.y; a[4 * q + 2] = t.z; a[4 * q + 3] = t.w;
    }
    float z[NCLS];
#pragma unroll
    for (int j = 0; j < NCLS; ++j) z[j] = b2[j];
#pragma unroll
    for (int i = 0; i < HID; ++i) {
        const float* w = W2 + (size_t)i * NCLS;
        float ai = a[i];
#pragma unroll
        for (int j = 0; j < NCLS; ++j) z[j] = fmaf(ai, w[j], z[j]);
    }
    float m = z[0];
#pragma unroll
    for (int j = 1; j < NCLS; ++j) m = fmaxf(m, z[j]);
    float s = 0.f;
#pragma unroll
    for (int j = 0; j < NCLS; ++j) s += __expf(z[j] - m);
    float ls = m + __logf(s);
    float* o = out + (size_t)node * NCLS;
#pragma unroll
    for (int q = 0; q < NCLS / 4; ++q)
        *reinterpret_cast<float4*>(o + 4 * q) =
            make_float4(z[4 * q] - ls, z[4 * q + 1] - ls, z[4 * q + 2] - ls, z[4 * q + 3] - ls);
}

extern "C" void kernel_launch(void* const* d_in, const int* in_sizes, int n_in,
                              void* d_out, int out_size, void* d_ws, size_t ws_size,
                              hipStream_t stream) {
    const float* x  = (const float*)d_in[0];
    const int*   ei = (const int*)d_in[1];
    const float* W1 = (const float*)d_in[2];
    const float* b1 = (const float*)d_in[3];
    const float* W2 = (const float*)d_in[4];
    const float* b2 = (const float*)d_in[5];
    float* out = (float*)d_out;

    const int N = in_sizes[0] / F_IN;   // 100000
    const int E = in_sizes[1] / 2;      // 3200000
    const int* row = ei;        // source nodes
    const int* col = ei + E;    // target nodes

    // workspace layout
    char* w = (char*)d_ws;
    float* dinv        = (float*)w;                 w += (size_t)N * 4;
    int*   cnt         = (int*)w;                   w += (size_t)N * 4;
    int*   ptr         = (int*)w;                   w += (size_t)(N + 1) * 4;
    int*   cur         = (int*)w;                   w += (size_t)N * 4;
    int*   rows_sorted = (int*)w;                   w += (size_t)E * 4;
    float* yp          = (float*)w;                 w += (size_t)N * HID * 4;
    float* hp          = (float*)w;                 w += (size_t)N * HID * 4;
    float* agg2        = (float*)w;                 w += (size_t)N * HID * 4;

    const int B = 256;
    k_zero_i<<<(N + B - 1) / B, B, 0, stream>>>(cnt, N);
    k_hist  <<<(E + B - 1) / B, B, 0, stream>>>(col, cnt, E);
    k_scan  <<<1, 1024, 0, stream>>>(cnt, ptr, cur, dinv, N);
    k_fill  <<<(E + B - 1) / B, B, 0, stream>>>(row, col, cur, rows_sorted, E);
    k_gemm1 <<<(N + B - 1) / B, B, 0, stream>>>(x, W1, dinv, yp, N);
    k_agg<true> <<<((N * 4) + B - 1) / B, B, 0, stream>>>(ptr, rows_sorted, yp, dinv, b1, hp, N);
    k_agg<false><<<((N * 4) + B - 1) / B, B, 0, stream>>>(ptr, rows_sorted, hp, dinv, nullptr, agg2, N);
    k_final <<<(N + B - 1) / B, B, 0, stream>>>(agg2, W2, b2, out, N);
}

// Round 3
// 805.615 us; speedup vs baseline: 1.9929x; 1.1177x over previous
//
#include <hip/hip_runtime.h>

#define F_IN 512
#define HID  16
#define NCLS 40
#define BSHIFT 13
#define MAXB 32

__global__ void k_zero_i(int* __restrict__ p, int n) {
    int i = blockIdx.x * blockDim.x + threadIdx.x;
    if (i < n) p[i] = 0;
}

// cnt[col[e]] += 1  (int atomics, 1 per edge, int4 loads)
__global__ void k_hist(const int* __restrict__ col, int* __restrict__ cnt, int ne) {
    int i = blockIdx.x * blockDim.x + threadIdx.x;
    int e0 = i * 4;
    if (e0 + 3 < ne) {
        int4 c = *reinterpret_cast<const int4*>(col + e0);
        atomicAdd(&cnt[c.x], 1);
        atomicAdd(&cnt[c.y], 1);
        atomicAdd(&cnt[c.z], 1);
        atomicAdd(&cnt[c.w], 1);
    } else {
        for (int e = e0; e < ne; ++e) atomicAdd(&cnt[col[e]], 1);
    }
}

// single-block exclusive scan of cnt -> ptr; cur = ptr copy; dinv = rsqrt(cnt+1);
// bucket cursors bcur[b] = ptr[min(b<<BSHIFT, n)]
__global__ void k_scan(const int* __restrict__ cnt, int* __restrict__ ptr,
                       int* __restrict__ cur, float* __restrict__ dinv,
                       int* __restrict__ bcur, int n, int nb) {
    __shared__ int sh[1024];
    int t = threadIdx.x;
    const int CH = (n + 1023) >> 10;
    int lo = t * CH, hi = lo + CH;
    if (lo > n) lo = n;
    if (hi > n) hi = n;
    int s = 0;
    for (int i = lo; i < hi; ++i) s += cnt[i];
    sh[t] = s;
    __syncthreads();
    for (int off = 1; off < 1024; off <<= 1) {
        int v = (t >= off) ? sh[t - off] : 0;
        __syncthreads();
        sh[t] += v;
        __syncthreads();
    }
    int run = (t == 0) ? 0 : sh[t - 1];
    for (int i = lo; i < hi; ++i) {
        int c = cnt[i];
        ptr[i] = run;
        cur[i] = run;
        dinv[i] = rsqrtf((float)(c + 1));
        run += c;
    }
    if (t == 1023) ptr[n] = run;  // == E
    __syncthreads();
    if (t < nb) {
        int node = t << BSHIFT;
        if (node > n) node = n;
        bcur[t] = ptr[node];
    }
}

// Phase A: partition (row,col) pairs into col-range buckets (bucket-contiguous, CSR-aligned)
__global__ void k_bucket(const int* __restrict__ row, const int* __restrict__ col,
                         int* __restrict__ bcur, int2* __restrict__ pairs, int ne) {
    __shared__ int lhist[MAXB];
    __shared__ int gbase[MAXB];
    int t = threadIdx.x;
    if (t < MAXB) lhist[t] = 0;
    __syncthreads();
    int base = blockIdx.x * 2048;
    int r[8], c[8], rk[8];
#pragma unroll
    for (int i = 0; i < 8; ++i) {
        int e = base + i * 256 + t;
        if (e < ne) {
            r[i] = row[e];
            c[i] = col[e];
            rk[i] = atomicAdd(&lhist[c[i] >> BSHIFT], 1);
        }
    }
    __syncthreads();
    if (t < MAXB && lhist[t] > 0) gbase[t] = atomicAdd(&bcur[t], lhist[t]);
    __syncthreads();
#pragma unroll
    for (int i = 0; i < 8; ++i) {
        int e = base + i * 256 + t;
        if (e < ne) pairs[gbase[c[i] >> BSHIFT] + rk[i]] = make_int2(r[i], c[i]);
    }
}

// Phase B: fill rows_sorted within L2-resident bucket windows
__global__ void k_fill2(const int2* __restrict__ pairs, int* __restrict__ cur,
                        int* __restrict__ rows_sorted, int ne) {
    int e = blockIdx.x * blockDim.x + threadIdx.x;
    if (e >= ne) return;
    int2 pc = pairs[e];
    int p = atomicAdd(&cur[pc.y], 1);
    rows_sorted[p] = pc.x;
}

// yp = dinv[node] * (x @ W1)   (prescaled by source dinv)
__global__ void k_gemm1(const float* __restrict__ x, const float* __restrict__ W1,
                        const float* __restrict__ dinv, float* __restrict__ yp, int n) {
    int node = blockIdx.x * blockDim.x + threadIdx.x;
    if (node >= n) return;
    const float* xr = x + (size_t)node * F_IN;
    float acc[HID];
#pragma unroll
    for (int j = 0; j < HID; ++j) acc[j] = 0.f;
    for (int k = 0; k < F_IN; k += 4) {
        float4 xv = *reinterpret_cast<const float4*>(xr + k);
        const float* w = W1 + (size_t)k * HID;
#pragma unroll
        for (int j = 0; j < HID; ++j) acc[j] = fmaf(xv.x, w[j], acc[j]);
#pragma unroll
        for (int j = 0; j < HID; ++j) acc[j] = fmaf(xv.y, w[HID + j], acc[j]);
#pragma unroll
        for (int j = 0; j < HID; ++j) acc[j] = fmaf(xv.z, w[2 * HID + j], acc[j]);
#pragma unroll
        for (int j = 0; j < HID; ++j) acc[j] = fmaf(xv.w, w[3 * HID + j], acc[j]);
    }
    float di = dinv[node];
    float4* o = reinterpret_cast<float4*>(yp + (size_t)node * HID);
#pragma unroll
    for (int q = 0; q < 4; ++q)
        o[q] = make_float4(acc[4 * q] * di, acc[4 * q + 1] * di,
                           acc[4 * q + 2] * di, acc[4 * q + 3] * di);
}

// Gather-reduce over CSR segment. 4 lanes per node, each lane owns a float4.
template <bool RELU>
__global__ void k_agg(const int* __restrict__ ptr, const int* __restrict__ rows_sorted,
                      const float* __restrict__ src, const float* __restrict__ dinv,
                      const float* __restrict__ b1, float* __restrict__ dst, int n) {
    int t = blockIdx.x * blockDim.x + threadIdx.x;
    int g = t >> 2;            // node
    if (g >= n) return;
    int q = (t & 3) << 2;      // float4 slot
    float4 acc = *reinterpret_cast<const float4*>(src + (size_t)g * HID + q);
    int s = ptr[g], e2 = ptr[g + 1];
    int k = s;
    for (; k + 1 < e2; k += 2) {
        int r0 = rows_sorted[k], r1 = rows_sorted[k + 1];
        float4 v0 = *reinterpret_cast<const float4*>(src + (size_t)r0 * HID + q);
        float4 v1 = *reinterpret_cast<const float4*>(src + (size_t)r1 * HID + q);
        acc.x += v0.x + v1.x; acc.y += v0.y + v1.y;
        acc.z += v0.z + v1.z; acc.w += v0.w + v1.w;
    }
    if (k < e2) {
        int r0 = rows_sorted[k];
        float4 v0 = *reinterpret_cast<const float4*>(src + (size_t)r0 * HID + q);
        acc.x += v0.x; acc.y += v0.y; acc.z += v0.z; acc.w += v0.w;
    }
    float d = dinv[g];
    float4 o;
    if (RELU) {
        float4 bb = *reinterpret_cast<const float4*>(b1 + q);
        o.x = d * fmaxf(fmaf(d, acc.x, bb.x), 0.f);
        o.y = d * fmaxf(fmaf(d, acc.y, bb.y), 0.f);
        o.z = d * fmaxf(fmaf(d, acc.z, bb.z), 0.f);
        o.w = d * fmaxf(fmaf(d, acc.w, bb.w), 0.f);
    } else {
        o.x = d * acc.x; o.y = d * acc.y; o.z = d * acc.z; o.w = d * acc.w;
    }
    *reinterpret_cast<float4*>(dst + (size_t)g * HID + q) = o;
}

// out = log_softmax(agg2 @ W2 + b2)
__global__ void k_final(const float* __restrict__ agg2, const float* __restrict__ W2,
                        const float* __restrict__ b2, float* __restrict__ out, int n) {
    int node = blockIdx.x * blockDim.x + threadIdx.x;
    if (node >= n) return;
    const float4* ar = reinterpret_cast<const float4*>(agg2 + (size_t)node * HID);
    float a[HID];
#pragma unroll
    for (int q = 0; q < 4; ++q) {
        float4 t = ar[q];
        a[4 * q] = t.x; a[4 * q + 1] = t.y; a[4 * q + 2] = t.z; a[4 * q + 3] = t.w;
    }
    float z[NCLS];
#pragma unroll
    for (int j = 0; j < NCLS; ++j) z[j] = b2[j];
#pragma unroll
    for (int i = 0; i < HID; ++i) {
        const float* w = W2 + (size_t)i * NCLS;
        float ai = a[i];
#pragma unroll
        for (int j = 0; j < NCLS; ++j) z[j] = fmaf(ai, w[j], z[j]);
    }
    float m = z[0];
#pragma unroll
    for (int j = 1; j < NCLS; ++j) m = fmaxf(m, z[j]);
    float s = 0.f;
#pragma unroll
    for (int j = 0; j < NCLS; ++j) s += __expf(z[j] - m);
    float ls = m + __logf(s);
    float* o = out + (size_t)node * NCLS;
#pragma unroll
    for (int q = 0; q < NCLS / 4; ++q)
        *reinterpret_cast<float4*>(o + 4 * q) =
            make_float4(z[4 * q] - ls, z[4 * q + 1] - ls, z[4 * q + 2] - ls, z[4 * q + 3] - ls);
}

extern "C" void kernel_launch(void* const* d_in, const int* in_sizes, int n_in,
                              void* d_out, int out_size, void* d_ws, size_t ws_size,
                              hipStream_t stream) {
    const float* x  = (const float*)d_in[0];
    const int*   ei = (const int*)d_in[1];
    const float* W1 = (const float*)d_in[2];
    const float* b1 = (const float*)d_in[3];
    const float* W2 = (const float*)d_in[4];
    const float* b2 = (const float*)d_in[5];
    float* out = (float*)d_out;

    const int N = in_sizes[0] / F_IN;   // 100000
    const int E = in_sizes[1] / 2;      // 3200000
    const int* row = ei;        // source nodes
    const int* col = ei + E;    // target nodes
    const int NB = (N + (1 << BSHIFT) - 1) >> BSHIFT;   // 13

    // workspace layout (pairs aliases yp/hp/agg2 — dead after k_fill2)
    char* w = (char*)d_ws;
    float* dinv        = (float*)w;   w += (size_t)N * 4;
    int*   cnt         = (int*)w;     w += (size_t)N * 4;
    int*   ptr         = (int*)w;     w += (size_t)(N + 1) * 4;
    int*   cur         = (int*)w;     w += (size_t)N * 4;
    int*   bcur        = (int*)w;     w += (size_t)MAXB * 4;
    int*   rows_sorted = (int*)w;     w += (size_t)E * 4;
    char*  uni         = w;           // union region
    int2*  pairs       = (int2*)uni;                       // 2E ints
    float* yp          = (float*)uni;                      // 16N floats
    float* hp          = yp + (size_t)N * HID;             // 16N floats
    float* agg2        = hp + (size_t)N * HID;             // 16N floats

    const int B = 256;
    k_zero_i<<<(N + B - 1) / B, B, 0, stream>>>(cnt, N);
    k_hist  <<<((E + 3) / 4 + B - 1) / B, B, 0, stream>>>(col, cnt, E);
    k_scan  <<<1, 1024, 0, stream>>>(cnt, ptr, cur, dinv, bcur, N, NB);
    k_bucket<<<(E + 2047) / 2048, B, 0, stream>>>(row, col, bcur, pairs, E);
    k_fill2 <<<(E + B - 1) / B, B, 0, stream>>>(pairs, cur, rows_sorted, E);
    k_gemm1 <<<(N + B - 1) / B, B, 0, stream>>>(x, W1, dinv, yp, N);
    k_agg<true> <<<((N * 4) + B - 1) / B, B, 0, stream>>>(ptr, rows_sorted, yp, dinv, b1, hp, N);
    k_agg<false><<<((N * 4) + B - 1) / B, B, 0, stream>>>(ptr, rows_sorted, hp, dinv, nullptr, agg2, N);
    k_final <<<(N + B - 1) / B, B, 0, stream>>>(agg2, W2, b2, out, N);
}

// Round 4
// 542.048 us; speedup vs baseline: 2.9620x; 1.4862x over previous
//
#include <hip/hip_runtime.h>

#define F_IN 512
#define HID  16
#define NCLS 40
#define BSHIFT 13
#define MAXB 32

__global__ void k_zero_i(int* __restrict__ p, int n) {
    int i = blockIdx.x * blockDim.x + threadIdx.x;
    if (i < n) p[i] = 0;
}

// cnt[col[e]] += 1  (int atomics, 1 per edge, int4 loads)
__global__ void k_hist(const int* __restrict__ col, int* __restrict__ cnt, int ne) {
    int i = blockIdx.x * blockDim.x + threadIdx.x;
    int e0 = i * 4;
    if (e0 + 3 < ne) {
        int4 c = *reinterpret_cast<const int4*>(col + e0);
        atomicAdd(&cnt[c.x], 1);
        atomicAdd(&cnt[c.y], 1);
        atomicAdd(&cnt[c.z], 1);
        atomicAdd(&cnt[c.w], 1);
    } else {
        for (int e = e0; e < ne; ++e) atomicAdd(&cnt[col[e]], 1);
    }
}

// ---- hierarchical scan: 1024 elements per block ----

__global__ void k_scan_partial(const int* __restrict__ cnt, int* __restrict__ bsum, int n) {
    __shared__ int sh[256];
    int t = threadIdx.x;
    int base = blockIdx.x * 1024 + t * 4;
    int s = 0;
    if (base + 3 < n) {
        int4 c = *reinterpret_cast<const int4*>(cnt + base);
        s = c.x + c.y + c.z + c.w;
    } else {
        for (int i = base; i < n && i < base + 4; ++i) s += cnt[i];
    }
    sh[t] = s;
    __syncthreads();
    for (int off = 128; off > 0; off >>= 1) {
        if (t < off) sh[t] += sh[t + off];
        __syncthreads();
    }
    if (t == 0) bsum[blockIdx.x] = sh[0];
}

// single tiny block: exclusive offsets of block sums (supports <=256 blocks)
__global__ void k_scan_bsum(const int* __restrict__ bsum, int* __restrict__ boff, int nblk) {
    __shared__ int sh[256];
    int t = threadIdx.x;
    int own = (t < nblk) ? bsum[t] : 0;
    sh[t] = own;
    __syncthreads();
    for (int off = 1; off < 256; off <<= 1) {
        int v = (t >= off) ? sh[t - off] : 0;
        __syncthreads();
        sh[t] += v;
        __syncthreads();
    }
    if (t < nblk) boff[t] = sh[t] - own;
}

// final: per-element exclusive prefix -> ptr/cur; dinv; bucket bases; ptr[n]
__global__ void k_scan_final(const int* __restrict__ cnt, const int* __restrict__ boff,
                             int* __restrict__ ptr, int* __restrict__ cur,
                             float* __restrict__ dinv, int* __restrict__ bcur, int n) {
    __shared__ int sh[256];
    int t = threadIdx.x;
    int base = blockIdx.x * 1024 + t * 4;
    int c[4];
    if (base + 3 < n) {
        int4 cc = *reinterpret_cast<const int4*>(cnt + base);
        c[0] = cc.x; c[1] = cc.y; c[2] = cc.z; c[3] = cc.w;
    } else {
#pragma unroll
        for (int i = 0; i < 4; ++i) c[i] = (base + i < n) ? cnt[base + i] : 0;
    }
    int s = c[0] + c[1] + c[2] + c[3];
    sh[t] = s;
    __syncthreads();
    for (int off = 1; off < 256; off <<= 1) {
        int v = (t >= off) ? sh[t - off] : 0;
        __syncthreads();
        sh[t] += v;
        __syncthreads();
    }
    int run = boff[blockIdx.x] + sh[t] - s;  // exclusive prefix at base
#pragma unroll
    for (int i = 0; i < 4; ++i) {
        int gi = base + i;
        if (gi < n) {
            ptr[gi] = run;
            cur[gi] = run;
            dinv[gi] = rsqrtf((float)(c[i] + 1));
            if ((gi & ((1 << BSHIFT) - 1)) == 0) bcur[gi >> BSHIFT] = run;
            run += c[i];
            if (gi == n - 1) ptr[n] = run;
        }
    }
}

// Phase A: partition (row,col) pairs into col-range buckets (bucket-contiguous, CSR-aligned)
__global__ void k_bucket(const int* __restrict__ row, const int* __restrict__ col,
                         int* __restrict__ bcur, int2* __restrict__ pairs, int ne) {
    __shared__ int lhist[MAXB];
    __shared__ int gbase[MAXB];
    int t = threadIdx.x;
    if (t < MAXB) lhist[t] = 0;
    __syncthreads();
    int base = blockIdx.x * 2048;
    int r[8], c[8], rk[8];
#pragma unroll
    for (int i = 0; i < 8; ++i) {
        int e = base + i * 256 + t;
        if (e < ne) {
            r[i] = row[e];
            c[i] = col[e];
            rk[i] = atomicAdd(&lhist[c[i] >> BSHIFT], 1);
        }
    }
    __syncthreads();
    if (t < MAXB && lhist[t] > 0) gbase[t] = atomicAdd(&bcur[t], lhist[t]);
    __syncthreads();
#pragma unroll
    for (int i = 0; i < 8; ++i) {
        int e = base + i * 256 + t;
        if (e < ne) pairs[gbase[c[i] >> BSHIFT] + rk[i]] = make_int2(r[i], c[i]);
    }
}

// Phase B: fill rows_sorted within L2-resident bucket windows
__global__ void k_fill2(const int2* __restrict__ pairs, int* __restrict__ cur,
                        int* __restrict__ rows_sorted, int ne) {
    int e = blockIdx.x * blockDim.x + threadIdx.x;
    if (e >= ne) return;
    int2 pc = pairs[e];
    int p = atomicAdd(&cur[pc.y], 1);
    rows_sorted[p] = pc.x;
}

// yp = dinv[node] * (x @ W1)   (prescaled by source dinv)
__global__ void k_gemm1(const float* __restrict__ x, const float* __restrict__ W1,
                        const float* __restrict__ dinv, float* __restrict__ yp, int n) {
    int node = blockIdx.x * blockDim.x + threadIdx.x;
    if (node >= n) return;
    const float* xr = x + (size_t)node * F_IN;
    float acc[HID];
#pragma unroll
    for (int j = 0; j < HID; ++j) acc[j] = 0.f;
    for (int k = 0; k < F_IN; k += 4) {
        float4 xv = *reinterpret_cast<const float4*>(xr + k);
        const float* w = W1 + (size_t)k * HID;
#pragma unroll
        for (int j = 0; j < HID; ++j) acc[j] = fmaf(xv.x, w[j], acc[j]);
#pragma unroll
        for (int j = 0; j < HID; ++j) acc[j] = fmaf(xv.y, w[HID + j], acc[j]);
#pragma unroll
        for (int j = 0; j < HID; ++j) acc[j] = fmaf(xv.z, w[2 * HID + j], acc[j]);
#pragma unroll
        for (int j = 0; j < HID; ++j) acc[j] = fmaf(xv.w, w[3 * HID + j], acc[j]);
    }
    float di = dinv[node];
    float4* o = reinterpret_cast<float4*>(yp + (size_t)node * HID);
#pragma unroll
    for (int q = 0; q < 4; ++q)
        o[q] = make_float4(acc[4 * q] * di, acc[4 * q + 1] * di,
                           acc[4 * q + 2] * di, acc[4 * q + 3] * di);
}

// Gather-reduce over CSR segment. 4 lanes per node, each lane owns a float4.
template <bool RELU>
__global__ void k_agg(const int* __restrict__ ptr, const int* __restrict__ rows_sorted,
                      const float* __restrict__ src, const float* __restrict__ dinv,
                      const float* __restrict__ b1, float* __restrict__ dst, int n) {
    int t = blockIdx.x * blockDim.x + threadIdx.x;
    int g = t >> 2;            // node
    if (g >= n) return;
    int q = (t & 3) << 2;      // float4 slot
    float4 acc = *reinterpret_cast<const float4*>(src + (size_t)g * HID + q);
    int s = ptr[g], e2 = ptr[g + 1];
    int k = s;
    for (; k + 1 < e2; k += 2) {
        int r0 = rows_sorted[k], r1 = rows_sorted[k + 1];
        float4 v0 = *reinterpret_cast<const float4*>(src + (size_t)r0 * HID + q);
        float4 v1 = *reinterpret_cast<const float4*>(src + (size_t)r1 * HID + q);
        acc.x += v0.x + v1.x; acc.y += v0.y + v1.y;
        acc.z += v0.z + v1.z; acc.w += v0.w + v1.w;
    }
    if (k < e2) {
        int r0 = rows_sorted[k];
        float4 v0 = *reinterpret_cast<const float4*>(src + (size_t)r0 * HID + q);
        acc.x += v0.x; acc.y += v0.y; acc.z += v0.z; acc.w += v0.w;
    }
    float d = dinv[g];
    float4 o;
    if (RELU) {
        float4 bb = *reinterpret_cast<const float4*>(b1 + q);
        o.x = d * fmaxf(fmaf(d, acc.x, bb.x), 0.f);
        o.y = d * fmaxf(fmaf(d, acc.y, bb.y), 0.f);
        o.z = d * fmaxf(fmaf(d, acc.z, bb.z), 0.f);
        o.w = d * fmaxf(fmaf(d, acc.w, bb.w), 0.f);
    } else {
        o.x = d * acc.x; o.y = d * acc.y; o.z = d * acc.z; o.w = d * acc.w;
    }
    *reinterpret_cast<float4*>(dst + (size_t)g * HID + q) = o;
}

// out = log_softmax(agg2 @ W2 + b2)
__global__ void k_final(const float* __restrict__ agg2, const float* __restrict__ W2,
                        const float* __restrict__ b2, float* __restrict__ out, int n) {
    int node = blockIdx.x * blockDim.x + threadIdx.x;
    if (node >= n) return;
    const float4* ar = reinterpret_cast<const float4*>(agg2 + (size_t)node * HID);
    float a[HID];
#pragma unroll
    for (int q = 0; q < 4; ++q) {
        float4 t = ar[q];
        a[4 * q] = t.x; a[4 * q + 1] = t.y; a[4 * q + 2] = t.z; a[4 * q + 3] = t.w;
    }
    float z[NCLS];
#pragma unroll
    for (int j = 0; j < NCLS; ++j) z[j] = b2[j];
#pragma unroll
    for (int i = 0; i < HID; ++i) {
        const float* w = W2 + (size_t)i * NCLS;
        float ai = a[i];
#pragma unroll
        for (int j = 0; j < NCLS; ++j) z[j] = fmaf(ai, w[j], z[j]);
    }
    float m = z[0];
#pragma unroll
    for (int j = 1; j < NCLS; ++j) m = fmaxf(m, z[j]);
    float s = 0.f;
#pragma unroll
    for (int j = 0; j < NCLS; ++j) s += __expf(z[j] - m);
    float ls = m + __logf(s);
    float* o = out + (size_t)node * NCLS;
#pragma unroll
    for (int q = 0; q < NCLS / 4; ++q)
        *reinterpret_cast<float4*>(o + 4 * q) =
            make_float4(z[4 * q] - ls, z[4 * q + 1] - ls, z[4 * q + 2] - ls, z[4 * q + 3] - ls);
}

extern "C" void kernel_launch(void* const* d_in, const int* in_sizes, int n_in,
                              void* d_out, int out_size, void* d_ws, size_t ws_size,
                              hipStream_t stream) {
    const float* x  = (const float*)d_in[0];
    const int*   ei = (const int*)d_in[1];
    const float* W1 = (const float*)d_in[2];
    const float* b1 = (const float*)d_in[3];
    const float* W2 = (const float*)d_in[4];
    const float* b2 = (const float*)d_in[5];
    float* out = (float*)d_out;

    const int N = in_sizes[0] / F_IN;   // 100000
    const int E = in_sizes[1] / 2;      // 3200000
    const int* row = ei;        // source nodes
    const int* col = ei + E;    // target nodes
    const int NBLK = (N + 1023) / 1024; // 98 scan blocks

    // workspace layout (pairs aliases yp/hp/agg2 — dead after k_fill2)
    char* w = (char*)d_ws;
    float* dinv        = (float*)w;   w += (size_t)N * 4;
    int*   cnt         = (int*)w;     w += (size_t)N * 4;
    int*   ptr         = (int*)w;     w += (size_t)(N + 1) * 4;
    int*   cur         = (int*)w;     w += (size_t)N * 4;
    int*   bcur        = (int*)w;     w += (size_t)MAXB * 4;
    int*   bsum        = (int*)w;     w += 256 * 4;
    int*   boff        = (int*)w;     w += 256 * 4;
    int*   rows_sorted = (int*)w;     w += (size_t)E * 4;
    char*  uni         = w;           // union region
    int2*  pairs       = (int2*)uni;                       // 2E ints
    float* yp          = (float*)uni;                      // 16N floats
    float* hp          = yp + (size_t)N * HID;             // 16N floats
    float* agg2        = hp + (size_t)N * HID;             // 16N floats

    const int B = 256;
    k_zero_i      <<<(N + B - 1) / B, B, 0, stream>>>(cnt, N);
    k_hist        <<<((E + 3) / 4 + B - 1) / B, B, 0, stream>>>(col, cnt, E);
    k_scan_partial<<<NBLK, B, 0, stream>>>(cnt, bsum, N);
    k_scan_bsum   <<<1, 256, 0, stream>>>(bsum, boff, NBLK);
    k_scan_final  <<<NBLK, B, 0, stream>>>(cnt, boff, ptr, cur, dinv, bcur, N);
    k_bucket      <<<(E + 2047) / 2048, B, 0, stream>>>(row, col, bcur, pairs, E);
    k_fill2       <<<(E + B - 1) / B, B, 0, stream>>>(pairs, cur, rows_sorted, E);
    k_gemm1       <<<(N + B - 1) / B, B, 0, stream>>>(x, W1, dinv, yp, N);
    k_agg<true>   <<<((N * 4) + B - 1) / B, B, 0, stream>>>(ptr, rows_sorted, yp, dinv, b1, hp, N);
    k_agg<false>  <<<((N * 4) + B - 1) / B, B, 0, stream>>>(ptr, rows_sorted, hp, dinv, nullptr, agg2, N);
    k_final       <<<(N + B - 1) / B, B, 0, stream>>>(agg2, W2, b2, out, N);
}